// Round 10
// baseline (124.923 us; speedup 1.0000x reference)
//
#include <hip/hip_runtime.h>

// Segmented CRF forward (OneCrfCCKSDecoder), exp-domain + MFMA, R10.
// T=128, B=512, E=128, EVENTLEN=8, NEG=-10000.
//
// R9 post-mortem: wall = per-step chain x127 (wg-count independent);
// 8-wave barrier + 32 ds_read_b128/CU-step ~= 1060cyc/step. R10 shortens the
// chain: 4 waves x 2 j-tiles each (256 thr, grid 32). Per-CU reads halve
// (16 b128/step), barrier skew over 4 waves, 8 MFMAs/wave in 4 independent
// chains. MFMA layouts + renorm scheme identical to R9 (absmax 0.0):
//   A[m=lane&15][k=32kap+8q+i], B[k=32kap+8q+i][n=lane&15], D[m=4q+r][n],
//   H 16B chunks XOR-swizzled by bloc; fixed e^-6/step scale folded into h
//   with exact M bookkeeping + exact per-batch max renorm at each boundary.
// E row 0 and te[127] are exactly 0 (matches fp32 exp(-10000)=0).

typedef _Float16 f16x4 __attribute__((ext_vector_type(4)));
typedef _Float16 f16x8 __attribute__((ext_vector_type(8)));
typedef float    f32x4 __attribute__((ext_vector_type(4)));

#define NEG_VAL   (-10000.0f)
#define C_SCALE   0.0024787521766663585f   // e^-6
#define LOG_C     6.0f

// order own LDS writes + join workgroup; does NOT drain vmcnt (feat
// prefetch loads stay in flight across the barrier)
#define LDS_BARRIER() asm volatile("s_waitcnt lgkmcnt(0)\n\ts_barrier" ::: "memory")

__global__ __launch_bounds__(256)
void crf_fwd(const float* __restrict__ feats,   // [128][512][128] f32
             const float* __restrict__ trans,   // [128][128] f32
             float* __restrict__ out)
{
    const int tid  = threadIdx.x;
    const int w    = tid >> 6;         // wave id 0..3; owns j-tiles 2w, 2w+1
    const int lane = tid & 63;
    const int bloc = lane & 15;        // batch-in-tile (n role; m role for A)
    const int q    = lane >> 4;        // quad 0..3
    const int b    = blockIdx.x * 16 + bloc;   // global batch

    // ---- A fragments for 2 tiles: rows j = 16*(2w+tile) + bloc ----
    f16x8 Afrag[2][4];
    #pragma unroll
    for (int tile = 0; tile < 2; ++tile) {
        const float* rowp = trans + (size_t)(16 * (2 * w + tile) + bloc) * 128;
        #pragma unroll
        for (int kap = 0; kap < 4; ++kap) {
            const f32x4* p = (const f32x4*)(rowp + 32 * kap + 8 * q);
            f32x4 x = p[0], y = p[1];
            f16x8 f;
            f[0] = (_Float16)__expf(x[0]); f[1] = (_Float16)__expf(x[1]);
            f[2] = (_Float16)__expf(x[2]); f[3] = (_Float16)__expf(x[3]);
            f[4] = (_Float16)__expf(y[0]); f[5] = (_Float16)__expf(y[1]);
            f[6] = (_Float16)__expf(y[2]); f[7] = (_Float16)__expf(y[3]);
            Afrag[tile][kap] = f;
        }
    }
    // te in D layout for own tiles: te[tile][r] = exp(trans[127][16*(2w+tile)+4q+r])
    f32x4 te0, te1;
    {
        f32x4 x = *(const f32x4*)(trans + 127 * 128 + 16 * (2 * w + 0) + 4 * q);
        te0[0] = __expf(x[0]); te0[1] = __expf(x[1]);
        te0[2] = __expf(x[2]); te0[3] = __expf(x[3]);
        f32x4 y = *(const f32x4*)(trans + 127 * 128 + 16 * (2 * w + 1) + 4 * q);
        te1[0] = __expf(y[0]); te1[1] = __expf(y[1]);
        te1[2] = __expf(y[2]); te1[3] = __expf(y[3]);
    }

    // ---- LDS: H (16 batches x 128 k f16, 16B chunks XOR-swizzled by bloc),
    //           Spart/Mpart ([bloc][w]) for boundary exchange ----
    __shared__ __align__(16) char  Hbuf[4096];
    __shared__ float Spart[16 * 4];
    __shared__ float Mpart[16 * 4];

    // write: j-slice k=16*(2w+tile)+4q+r -> chunk (4w+2*tile+(q>>1)), half q&1
    const int waddr0 = bloc * 256 + (((4 * w + 0 + (q >> 1)) ^ bloc) * 16) + 8 * (q & 1);
    const int waddr1 = bloc * 256 + (((4 * w + 2 + (q >> 1)) ^ bloc) * 16) + 8 * (q & 1);
    int raddr[4];
    #pragma unroll
    for (int kap = 0; kap < 4; ++kap)
        raddr[kap] = bloc * 256 + (((4 * kap + q) ^ bloc) * 16);

    // ---- feat pipeline: lane needs feat[t][b][16*(2w+tile)+4q+r], tile=0,1
    const float* fb0 = feats + (size_t)b * 128 + 32 * w + 4 * q;       // tile 0
    const float* fb1 = fb0 + 16;                                        // tile 1
    f32x4 efi0, efi1;       // exp(feat[t]) * scale for next update's h
    f32x4 r1v0, r1v1, r2v0, r2v1;
    {
        f32x4 x = *(const f32x4*)(fb0 + 1 * 65536);
        f32x4 y = *(const f32x4*)(fb1 + 1 * 65536);
        efi0[0] = __expf(x[0]) * C_SCALE; efi0[1] = __expf(x[1]) * C_SCALE;
        efi0[2] = __expf(x[2]) * C_SCALE; efi0[3] = __expf(x[3]) * C_SCALE;
        efi1[0] = __expf(y[0]) * C_SCALE; efi1[1] = __expf(y[1]) * C_SCALE;
        efi1[2] = __expf(y[2]) * C_SCALE; efi1[3] = __expf(y[3]) * C_SCALE;
        r1v0 = *(const f32x4*)(fb0 + 2 * 65536);
        r1v1 = *(const f32x4*)(fb1 + 2 * 65536);
        r2v0 = *(const f32x4*)(fb0 + 3 * 65536);
        r2v1 = *(const f32x4*)(fb1 + 3 * 65536);
    }
    float logc_cur = LOG_C;            // log of scale baked into current efi

    f32x4 acc0 = {1.f, 1.f, 1.f, 1.f}; // u[b][j], j = 16*(2w)   + 4q + r
    f32x4 acc1 = {1.f, 1.f, 1.f, 1.f}; // u[b][j], j = 16*(2w+1) + 4q + r
    float M     = (b == 0) ? 0.0f : NEG_VAL;  // init_fv zeroes only batch-0 row
    float alpha = 0.0f;

    #pragma unroll 8
    for (int t = 1; t < 128; ++t) {
        const bool upd = (t & 7) != 0;
        float sc_next = C_SCALE;       // scale for t+1's efi (boundary overrides)
        float lg_next = LOG_C;

        if (upd) {
            // ---- publish h = u * efi (scale inside efi; M bookkeeping) ----
            M += logc_cur;
            f16x4 h0, h1;
            h0[0] = (_Float16)(acc0[0] * efi0[0]);
            h0[1] = (_Float16)(acc0[1] * efi0[1]);
            h0[2] = (_Float16)(acc0[2] * efi0[2]);
            h0[3] = (_Float16)(acc0[3] * efi0[3]);
            h1[0] = (_Float16)(acc1[0] * efi1[0]);
            h1[1] = (_Float16)(acc1[1] * efi1[1]);
            h1[2] = (_Float16)(acc1[2] * efi1[2]);
            h1[3] = (_Float16)(acc1[3] * efi1[3]);
            *(f16x4*)(Hbuf + waddr0) = h0;
            *(f16x4*)(Hbuf + waddr1) = h1;
            LDS_BARRIER();

            f16x8 B0 = *(const f16x8*)(Hbuf + raddr[0]);
            f16x8 B1 = *(const f16x8*)(Hbuf + raddr[1]);
            f16x8 B2 = *(const f16x8*)(Hbuf + raddr[2]);
            f16x8 B3 = *(const f16x8*)(Hbuf + raddr[3]);

            // ---- 8 MFMAs, four independent chains of 2 ----
            f32x4 z = {0.f, 0.f, 0.f, 0.f};
            f32x4 da0 = __builtin_amdgcn_mfma_f32_16x16x32_f16(Afrag[0][0], B0, z, 0, 0, 0);
            f32x4 db0 = __builtin_amdgcn_mfma_f32_16x16x32_f16(Afrag[0][1], B1, z, 0, 0, 0);
            f32x4 da1 = __builtin_amdgcn_mfma_f32_16x16x32_f16(Afrag[1][0], B0, z, 0, 0, 0);
            f32x4 db1 = __builtin_amdgcn_mfma_f32_16x16x32_f16(Afrag[1][1], B1, z, 0, 0, 0);
            da0 = __builtin_amdgcn_mfma_f32_16x16x32_f16(Afrag[0][2], B2, da0, 0, 0, 0);
            db0 = __builtin_amdgcn_mfma_f32_16x16x32_f16(Afrag[0][3], B3, db0, 0, 0, 0);
            da1 = __builtin_amdgcn_mfma_f32_16x16x32_f16(Afrag[1][2], B2, da1, 0, 0, 0);
            db1 = __builtin_amdgcn_mfma_f32_16x16x32_f16(Afrag[1][3], B3, db1, 0, 0, 0);
            acc0 = da0 + db0;
            acc1 = da1 + db1;
        } else {
            // ---- boundary: per-wave partials (sum for alpha, max for renorm)
            float s = acc0[0] * te0[0] + acc0[1] * te0[1]
                    + acc0[2] * te0[2] + acc0[3] * te0[3]
                    + acc1[0] * te1[0] + acc1[1] * te1[1]
                    + acc1[2] * te1[2] + acc1[3] * te1[3];
            float m = fmaxf(fmaxf(fmaxf(acc0[0], acc0[1]), fmaxf(acc0[2], acc0[3])),
                            fmaxf(fmaxf(acc1[0], acc1[1]), fmaxf(acc1[2], acc1[3])));
            s += __shfl_xor(s, 16, 64);
            s += __shfl_xor(s, 32, 64);
            m = fmaxf(m, __shfl_xor(m, 16, 64));
            m = fmaxf(m, __shfl_xor(m, 32, 64));
            if (q == 0) {
                Spart[bloc * 4 + w] = s;
                Mpart[bloc * 4 + w] = m;
            }
            LDS_BARRIER();

            f32x4 sa = *(const f32x4*)&Spart[bloc * 4];
            f32x4 ma = *(const f32x4*)&Mpart[bloc * 4];
            float r    = (sa[0] + sa[1]) + (sa[2] + sa[3]);
            float cmax = fmaxf(fmaxf(ma[0], ma[1]), fmaxf(ma[2], ma[3]));

            alpha += M + __logf(r);    // per-batch, replicated over q & waves
            // exact renorm folded into the NEXT update's scale
            sc_next = C_SCALE * __builtin_amdgcn_rcpf(cmax);
            lg_next = LOG_C + __logf(cmax);
        }

        // ---- rotate feat pipeline; build efi for t+1 with chosen scale ----
        if (t + 1 < 128) {
            efi0[0] = __expf(r1v0[0]) * sc_next; efi0[1] = __expf(r1v0[1]) * sc_next;
            efi0[2] = __expf(r1v0[2]) * sc_next; efi0[3] = __expf(r1v0[3]) * sc_next;
            efi1[0] = __expf(r1v1[0]) * sc_next; efi1[1] = __expf(r1v1[1]) * sc_next;
            efi1[2] = __expf(r1v1[2]) * sc_next; efi1[3] = __expf(r1v1[3]) * sc_next;
            logc_cur = lg_next;
            r1v0 = r2v0; r1v1 = r2v1;
            if (t + 3 < 128) {
                r2v0 = *(const f32x4*)(fb0 + (size_t)(t + 3) * 65536);
                r2v1 = *(const f32x4*)(fb1 + (size_t)(t + 3) * 65536);
            }
        }
    }

    // ---- terminal accumulation (sum exchange only) ----
    {
        float s = acc0[0] * te0[0] + acc0[1] * te0[1]
                + acc0[2] * te0[2] + acc0[3] * te0[3]
                + acc1[0] * te1[0] + acc1[1] * te1[1]
                + acc1[2] * te1[2] + acc1[3] * te1[3];
        s += __shfl_xor(s, 16, 64);
        s += __shfl_xor(s, 32, 64);
        if (q == 0) Spart[bloc * 4 + w] = s;
        LDS_BARRIER();
        f32x4 sa = *(const f32x4*)&Spart[bloc * 4];
        float r = (sa[0] + sa[1]) + (sa[2] + sa[3]);
        alpha += M + __logf(r);
    }

    // alpha replicated across q and waves; reduce in wave 0 (4x q-copies).
    if (w == 0) {
        float v = alpha;
        #pragma unroll
        for (int off = 1; off < 64; off <<= 1)
            v += __shfl_xor(v, off, 64);
        if (lane == 0)
            atomicAdd(out, v * (1.0f / (4.0f * 512.0f * 16.0f)));
    }
}

extern "C" void kernel_launch(void* const* d_in, const int* in_sizes, int n_in,
                              void* d_out, int out_size, void* d_ws, size_t ws_size,
                              hipStream_t stream) {
    const float* feats = (const float*)d_in[0];   // [128,512,128] f32
    const float* trans = (const float*)d_in[1];   // [128,128] f32
    float* out = (float*)d_out;                   // scalar f32

    hipMemsetAsync(out, 0, sizeof(float), stream);
    crf_fwd<<<32, 256, 0, stream>>>(feats, trans, out);
}